// Round 6
// baseline (474.983 us; speedup 1.0000x reference)
//
#include <hip/hip_runtime.h>
#include <math.h>

// Problem constants: B=4, T=512, S=1024, H=768, V=50257
#define BB 4
#define TT 512
#define SS 1024
#define HH 768
#define VV 50257
#define NW 1571            // ceil(V/32) bitmap words per batch
#define NWP 1600           // uint2 stride per batch for bmpre_g (>= NW+1)
#define NPROJ 1536         // proj blocks (6144 rows / 4 waves)
#define NROWS (BB * TT)    // 2048 logits rows
#define NV (NROWS * VV)    // 102,926,336 logits floats (divisible by 4)
#define NG (NV / 4)        // 25,731,584 float4 groups
#define K2_GRID 768        // 3 blocks/CU * 256 CUs — exactly full residency

// ---------------------------------------------------------------------------
// Kernel P (unchanged from R5): blocks [0,1536) projections; [1536,1540)
// per-batch bitmap/prefix/rank setup, bm|pre interleaved as uint2 with a
// zero sentinel at index NW.
// ---------------------------------------------------------------------------
__global__ __launch_bounds__(256) void prep_kernel(
    const float* __restrict__ src, const float* __restrict__ tgt,
    const float* __restrict__ W, const float* __restrict__ bptr,
    const int* __restrict__ ids,
    float* __restrict__ src_proj, float* __restrict__ tgt_proj,
    uint2* __restrict__ bmpre_g, unsigned short* __restrict__ rank_g)
{
    __shared__ unsigned bm[NW];
    __shared__ unsigned pre[NW];
    __shared__ unsigned scan[256];
    const int tid = threadIdx.x;

    if (blockIdx.x < NPROJ) {
        const int wave = tid >> 6;
        const int lane = tid & 63;
        const int row  = blockIdx.x * 4 + wave;   // 0 .. 6143

        const float* vec;
        const float* w;
        if (row < BB * SS) { vec = src + (size_t)row * HH;            w = W; }
        else               { vec = tgt + (size_t)(row - BB*SS) * HH;  w = W + HH; }
        const float4* v4 = (const float4*)vec;
        const float4* w4 = (const float4*)w;

        float acc = 0.f;
#pragma unroll
        for (int k = 0; k < 3; ++k) {
            float4 a = v4[k * 64 + lane];
            float4 b = w4[k * 64 + lane];
            acc += a.x * b.x + a.y * b.y + a.z * b.z + a.w * b.w;
        }
#pragma unroll
        for (int off = 32; off > 0; off >>= 1) acc += __shfl_down(acc, off);
        if (lane == 0) {
            if (row < BB * SS) src_proj[row] = acc;
            else               tgt_proj[row - BB * SS] = acc + bptr[0];
        }
        return;
    }

    const int b = blockIdx.x - NPROJ;

    for (int i = tid; i < NW; i += 256) bm[i] = 0u;
    __syncthreads();
    const int* idb = ids + b * SS;
    for (int s = tid; s < SS; s += 256) {
        const int v = idb[s];
        atomicOr(&bm[v >> 5], 1u << (v & 31));
    }
    __syncthreads();

    unsigned cnt[7];
    unsigned local = 0;
    const int w0 = tid * 7;                 // 256*7 = 1792 >= 1571
#pragma unroll
    for (int k = 0; k < 7; ++k) {
        const int w = w0 + k;
        cnt[k] = local;
        local += (w < NW) ? (unsigned)__popc(bm[w]) : 0u;
    }
    scan[tid] = local;
    __syncthreads();
    for (int off = 1; off < 256; off <<= 1) {
        const unsigned mine = scan[tid];
        const unsigned add  = (tid >= off) ? scan[tid - off] : 0u;
        __syncthreads();
        scan[tid] = mine + add;
        __syncthreads();
    }
    const unsigned excl = (tid > 0) ? scan[tid - 1] : 0u;
#pragma unroll
    for (int k = 0; k < 7; ++k) {
        const int w = w0 + k;
        if (w < NW) {
            const unsigned p = excl + cnt[k];
            pre[w] = p;
            bmpre_g[b * NWP + w] = make_uint2(bm[w], p);
        }
    }
    if (tid == 0) bmpre_g[b * NWP + NW] = make_uint2(0u, 0u);  // sentinel
    __syncthreads();
    for (int s = tid; s < SS; s += 256) {
        const int v = idb[s];
        const unsigned w = (unsigned)v >> 5, bit = (unsigned)v & 31u;
        const unsigned r = pre[w] + (unsigned)__popc(bm[w] & ((1u << bit) - 1u));
        rank_g[b * SS + s] = (unsigned short)r;
    }
}

// ---------------------------------------------------------------------------
// Kernel K1 (new): one block per row. Materializes dval[row][rank] (4 KB
// contiguous per row) = segment-summed attention values, and p_gen.
// Decouples "row's LUT values" from "block that writes row's output",
// enabling the globally-ordered sweep in K2.
// ---------------------------------------------------------------------------
__global__ __launch_bounds__(256) void val_kernel(
    const float* __restrict__ attn,
    const float* __restrict__ src_proj,
    const float* __restrict__ tgt_proj,
    const unsigned short* __restrict__ rank_g,
    float* __restrict__ dval,
    float* __restrict__ out)
{
    __shared__ float vals[SS];
    __shared__ float wsum[4];
    const int row = blockIdx.x;     // 0 .. 2047
    const int b   = row >> 9;
    const int tid = threadIdx.x;

    ((float4*)vals)[tid] = make_float4(0.f, 0.f, 0.f, 0.f);
    __syncthreads();

    const float4  a = ((const float4*)(attn + (size_t)row * SS))[tid];
    const float4  p = ((const float4*)(src_proj + b * SS))[tid];
    const ushort4 r = ((const ushort4*)(rank_g + b * SS))[tid];
    atomicAdd(&vals[r.x], a.x);
    atomicAdd(&vals[r.y], a.y);
    atomicAdd(&vals[r.z], a.z);
    atomicAdd(&vals[r.w], a.w);
    float acc = a.x * p.x + a.y * p.y + a.z * p.z + a.w * p.w;
#pragma unroll
    for (int off = 32; off > 0; off >>= 1) acc += __shfl_down(acc, off);
    if ((tid & 63) == 0) wsum[tid >> 6] = acc;
    __syncthreads();   // vals final + wsum visible

    ((float4*)(dval + ((size_t)row << 10)))[tid] = ((float4*)vals)[tid];
    if (tid == 0) {
        const float x = wsum[0] + wsum[1] + wsum[2] + wsum[3] + tgt_proj[row];
        out[row] = 1.f / (1.f + expf(-x));
    }
}

// gather one element of the 4-wide window; t = s + J, word w (+1 if t>=32)
#define GELEM(J, DST)                                                       \
    if (m4 & (1u << (J))) {                                                 \
        const unsigned t  = (unsigned)s + (J);                              \
        const unsigned bw = (t >= 32u) ? bp1.x : bp0.x;                     \
        const unsigned pw = (t >= 32u) ? bp1.y : bp0.y;                     \
        const unsigned bt = t & 31u;                                        \
        DST = dvrow[pw + (unsigned)__popc(bw & ((1u << bt) - 1u))];         \
    }

// ---------------------------------------------------------------------------
// Kernel K2 (the bet): FILL-SHAPED global sweep. 768 fully-resident blocks
// grid-stride over all 25.7M float4 groups of the flat logits region — at
// any instant the whole machine writes ONE contiguous ~3MB window that
// marches through the 412MB output, exactly like the 6.1 TB/s poison fill.
// Per group: magic-div to (row,v), LDS nibble test (all 4 batches' bm|pre
// in LDS), rare gather from the L1-hot 4KB dval row, aligned float4 store.
// Row-straddling groups (1536 total) take a scalar slow path.
// ---------------------------------------------------------------------------
__global__ __launch_bounds__(256) void sweep_kernel(
    const uint2* __restrict__ bmpre_g,
    const float* __restrict__ dval,
    float* __restrict__ out)
{
    __shared__ uint2 bmpre[4 * (NW + 1)];
    const int tid = threadIdx.x;

    for (int i = tid; i < 4 * (NW + 1); i += 256) {
        const int b = i / (NW + 1);
        const int w = i - b * (NW + 1);
        bmpre[i] = bmpre_g[b * NWP + w];
    }
    __syncthreads();

    float* logits = out + NROWS;
    const int stride = K2_GRID * 256;
    for (int g = blockIdx.x * 256 + tid; g < NG; g += stride) {
        const int f0 = g << 2;
        const unsigned r = (unsigned)f0 / VV;          // compiler magic-div
        const int v0 = f0 - (int)(r * VV);
        if (v0 + 3 < VV) {                             // fast: group in row r
            const uint2* bp = bmpre + ((r >> 9) * (NW + 1));
            const float* dvrow = dval + ((size_t)r << 10);
            const int s = v0 & 31;
            const int w = v0 >> 5;
            const uint2 bp0 = bp[w];
            const uint2 bp1 = bp[w + 1];               // sentinel-safe
            unsigned m4 = bp0.x >> s;
            if (s >= 29) m4 |= (bp1.x << (32 - s));
            m4 &= 15u;
            float e0 = 0.f, e1 = 0.f, e2 = 0.f, e3 = 0.f;
            if (m4) { GELEM(0, e0) GELEM(1, e1) GELEM(2, e2) GELEM(3, e3) }
            *(float4*)(logits + f0) = make_float4(e0, e1, e2, e3);
        } else {                                       // straddle slow path
#pragma unroll
            for (int j = 0; j < 4; ++j) {
                const int f = f0 + j;
                const unsigned re = (unsigned)f / VV;
                const int ve = f - (int)(re * VV);
                const uint2 bw = bmpre[(re >> 9) * (NW + 1) + (ve >> 5)];
                const unsigned bt = (unsigned)ve & 31u;
                float e = 0.f;
                if ((bw.x >> bt) & 1u)
                    e = dval[((size_t)re << 10) + bw.y
                             + (unsigned)__popc(bw.x & ((1u << bt) - 1u))];
                logits[f] = e;
            }
        }
    }
}

extern "C" void kernel_launch(void* const* d_in, const int* in_sizes, int n_in,
                              void* d_out, int out_size, void* d_ws, size_t ws_size,
                              hipStream_t stream) {
    const int*   ids  = (const int*)d_in[0];    // [B,S]
    const float* attn = (const float*)d_in[1];  // [B,T,S]
    const float* src  = (const float*)d_in[2];  // [B,S,H]
    const float* tgt  = (const float*)d_in[3];  // [B,T,H]
    const float* W    = (const float*)d_in[4];  // [2H,1]
    const float* bp   = (const float*)d_in[5];  // [1]

    float* out = (float*)d_out;                 // [B*T (p_gen) | B*T*V]

    // ws layout (all 16B-aligned)
    float*          src_proj = (float*)d_ws;                          // 4096 f
    float*          tgt_proj = src_proj + BB * SS;                    // 2048 f
    uint2*          bmpre_g  = (uint2*)(tgt_proj + BB * TT);          // 4*1600 uint2
    unsigned short* rank_g   = (unsigned short*)(bmpre_g + BB * NWP); // 4096 u16
    float*          dval     = (float*)(rank_g + BB * SS);            // 2048*1024 f (8 MB)

    prep_kernel<<<NPROJ + BB, 256, 0, stream>>>(
        src, tgt, W, bp, ids, src_proj, tgt_proj, bmpre_g, rank_g);
    val_kernel<<<NROWS, 256, 0, stream>>>(
        attn, src_proj, tgt_proj, rank_g, dval, out);
    sweep_kernel<<<K2_GRID, 256, 0, stream>>>(
        bmpre_g, dval, out);
}